// Round 14
// baseline (464.912 us; speedup 1.0000x reference)
//
#include <hip/hip_runtime.h>
#include <hip/hip_bf16.h>

typedef short short8 __attribute__((ext_vector_type(8)));
typedef float floatx4 __attribute__((ext_vector_type(4)));

#define NGROUP 512
#define RREG 256
#define D 512
#define FBAR_ELEMS (NGROUP * D)   // 262144

__device__ __forceinline__ unsigned short f2bf(float f) {
    unsigned int u = __float_as_uint(f);
    unsigned int r = (u + 0x7fffu + ((u >> 16) & 1u)) >> 16;
    return (unsigned short)r;
}
__device__ __forceinline__ float bf2f(unsigned short h) {
    return __uint_as_float(((unsigned int)h) << 16);
}
__device__ __forceinline__ float fast_tanh(float x) {
    float cx = fminf(fmaxf(x, -9.5f), 9.5f);
    float e  = __builtin_amdgcn_exp2f(cx * 2.8853900817779268f);  // e^{2cx}
    return (e - 1.f) * __builtin_amdgcn_rcpf(e + 1.f);
}

// ---- kernel 1: W1 fp32 -> bf16, PRE-SWIZZLED 64-col full-K chunks (R13 verbatim).
// A 32-col chunk nc is the contiguous 32 KiB at byte nc*32768 of this image,
// with identical read-swizzle (col&7)<<4 (16|32 vanish mod 8).
__global__ __launch_bounds__(256) void conv_w1(const float* __restrict__ W1,
                                               unsigned short* __restrict__ W1s) {
    int tid = blockIdx.x * 256 + threadIdx.x;   // 0..65535
    int G = tid * 8;                            // byte offset in 512 KiB
    int nc = G >> 16;
    int L = G & 65535;
    int col_local = L >> 10;
    int sw = L & 1023;
    int k16 = (sw ^ ((col_local & 7) << 4)) >> 4;
    int j0 = (sw & 15) >> 1;                    // 0 or 4
    int col = nc * 64 + col_local;
    const float* src = W1 + col * 512 + k16 * 8 + j0;
    float4 v = *reinterpret_cast<const float4*>(src);
    ushort4 o;
    o.x = f2bf(v.x); o.y = f2bf(v.y); o.z = f2bf(v.z); o.w = f2bf(v.w);
    *reinterpret_cast<ushort4*>((char*)W1s + G) = o;
}

// ---- kernel 2: fully fused per-group kernel, reuse-2 GEMM ----
// 512 blocks x 512 threads (8 waves x 32 rows = 256 rows = one (b,n) group).
// A: TWO 16-row bf16 tiles per wave in registers (128 VGPR) loaded direct
// from x in MFMA fragment layout; ss->inv via shuffles (no LDS, no staging).
// amdgpu_waves_per_eu(2) raises the VGPR cap to 256 (R2-R13 lesson:
// launch_bounds arg2 never did; we always achieve only 2 waves/EU anyway).
// B: 32-col full-K chunks (32 KB) DMA'd into 2x32KB LDS dbuf; per chunk:
// own-wave vmcnt(0) + raw s_barrier (no cross-wave vmcnt convoy), prefetch
// issued a full chunk-compute (~800cy) ahead. Each B ds_read feeds 2 MFMAs
// (reuse 2) -> LDS pipe time halves vs R13 (the measured 82us wall).
// Post-GEMM: in-block softmax + pooling FROM REGISTER A-frags (R4-proven),
// eliminating the pool kernel's 268 MB x re-read. LDS scratch aliases B_lds.
__global__ __attribute__((amdgpu_flat_work_group_size(512, 512), amdgpu_waves_per_eu(2)))
void fused_group(
    const float* __restrict__ x, const unsigned short* __restrict__ W1s,
    const float* __restrict__ b1, const float* __restrict__ W2v,
    float* __restrict__ out) {

    __shared__ char B_lds[2][32768];   // 64 KiB total

    const int t = threadIdx.x;
    const int lane = t & 63;
    const int w = t >> 6;          // wave 0..7
    const int cl = lane & 15;
    const int hi = lane >> 4;
    const int g = blockIdx.x;
    const size_t row0 = (size_t)g * RREG;

    // stage 32-col chunk nc into buf: 4 KB per wave, 4 DMA instrs
    auto stage = [&](int buf, int nc) {
        const char* gb = (const char*)W1s + nc * 32768 + w * 4096 + lane * 16;
        char* lb = &B_lds[buf][w * 4096];
        #pragma unroll
        for (int i = 0; i < 4; ++i) {
            __builtin_amdgcn_global_load_lds(
                (const __attribute__((address_space(1))) void*)(gb + i * 1024),
                (__attribute__((address_space(3))) void*)(lb + i * 1024),
                16, 0, 0);
        }
    };

    stage(0, 0);   // chunks 0,1 in flight during the A phase
    stage(1, 1);

    // ---- A phase: two 16-row tiles per wave, direct from x, fragment layout ----
    // Tile m: lane(cl,hi) owns row w*32+m*16+cl, frag c covers k=c*32+hi*8..+8.
    short8 a0[16], a1[16];
    float inv0, inv1;
    #pragma unroll
    for (int m = 0; m < 2; ++m) {
        const float* xp = x + (row0 + w * 32 + m * 16 + cl) * (size_t)D + hi * 8;
        float4 vv[16][2];
        #pragma unroll
        for (int c = 0; c < 16; ++c) {
            vv[c][0] = *reinterpret_cast<const float4*>(xp + c * 32);
            vv[c][1] = *reinterpret_cast<const float4*>(xp + c * 32 + 4);
        }
        float ss = 0.f;
        #pragma unroll
        for (int c = 0; c < 16; ++c) {
            float4 p = vv[c][0], q = vv[c][1];
            ss += p.x*p.x + p.y*p.y + p.z*p.z + p.w*p.w
                + q.x*q.x + q.y*q.y + q.z*q.z + q.w*q.w;
        }
        ss += __shfl_xor(ss, 16, 64);
        ss += __shfl_xor(ss, 32, 64);
        float inv = 1.0f / fmaxf(sqrtf(ss), 1e-12f);
        #pragma unroll
        for (int c = 0; c < 16; ++c) {
            float4 p = vv[c][0], q = vv[c][1];
            short8 s8;
            s8[0] = (short)f2bf(p.x); s8[1] = (short)f2bf(p.y);
            s8[2] = (short)f2bf(p.z); s8[3] = (short)f2bf(p.w);
            s8[4] = (short)f2bf(q.x); s8[5] = (short)f2bf(q.y);
            s8[6] = (short)f2bf(q.z); s8[7] = (short)f2bf(q.w);
            if (m == 0) a0[c] = s8; else a1[c] = s8;
        }
        if (m == 0) inv0 = inv; else inv1 = inv;
    }
    // acc row r = hi*4+i of tile m needs inv of that row (held by lane cl=r)
    float ivr[2][4];
    #pragma unroll
    for (int i = 0; i < 4; ++i) {
        ivr[0][i] = __shfl(inv0, hi * 4 + i, 16);
        ivr[1][i] = __shfl(inv1, hi * 4 + i, 16);
    }

    __syncthreads();   // all waves' A ready; chunks 0,1 landed (DMAs oldest)

    // ---- GEMM: 16 chunks of 32 cols x full K; reuse-2; 1 raw barrier/chunk ----
    float sp[2][4] = {{0.f,0.f,0.f,0.f},{0.f,0.f,0.f,0.f}};
    const int bswz = (cl & 7) << 4;

    for (int nc = 0; nc < 16; ++nc) {
        if (nc) {
            asm volatile("s_waitcnt vmcnt(0)" ::: "memory");  // own chunk-nc DMAs done
            __builtin_amdgcn_s_barrier();                     // all waves' portions done
            if (nc + 1 < 16) stage((nc + 1) & 1, nc + 1);     // safe: buf last read nc-1
        }
        const char* Bb = &B_lds[nc & 1][0];

        floatx4 acc00{0,0,0,0}, acc01{0,0,0,0}, acc10{0,0,0,0}, acc11{0,0,0,0};
        #pragma unroll
        for (int s = 0; s < 16; ++s) {
            const int kb = (s * 64 + hi * 16);
            short8 bf0 = *reinterpret_cast<const short8*>(Bb + cl * 1024 + (kb ^ bswz));
            short8 bf1 = *reinterpret_cast<const short8*>(Bb + (16 + cl) * 1024 + (kb ^ bswz));
            acc00 = __builtin_amdgcn_mfma_f32_16x16x32_bf16(a0[s], bf0, acc00, 0, 0, 0);
            acc10 = __builtin_amdgcn_mfma_f32_16x16x32_bf16(a1[s], bf0, acc10, 0, 0, 0);
            acc01 = __builtin_amdgcn_mfma_f32_16x16x32_bf16(a0[s], bf1, acc01, 0, 0, 0);
            acc11 = __builtin_amdgcn_mfma_f32_16x16x32_bf16(a1[s], bf1, acc11, 0, 0, 0);
        }

        // fold chunk into score partials: +b1, tanh, *w2
        #pragma unroll
        for (int f = 0; f < 2; ++f) {
            int col = nc * 32 + f * 16 + cl;
            float wv = W2v[col];
            float bb = b1[col];
            const floatx4& c0 = f ? acc01 : acc00;
            const floatx4& c1 = f ? acc11 : acc10;
            #pragma unroll
            for (int i = 0; i < 4; ++i) {
                sp[0][i] += wv * fast_tanh(c0[i] * ivr[0][i] + bb);
                sp[1][i] += wv * fast_tanh(c1[i] * ivr[1][i] + bb);
            }
        }
    }
    __syncthreads();   // GEMM done everywhere; B_lds becomes scratch

    // ---- LDS scratch aliases (all within buf0's 32 KB) ----
    float* scores_s = (float*)&B_lds[0][0];      // [256]
    float* F        = (float*)&B_lds[0][1024];   // [256]
    float* alpha_s  = (float*)&B_lds[0][2048];   // [256]
    float* wred     = (float*)&B_lds[0][4096];   // [8][512]

    // per-row scores: reduce sp over the 16 col-lanes; C/D row = hi*4+i
    #pragma unroll
    for (int m = 0; m < 2; ++m) {
        #pragma unroll
        for (int i = 0; i < 4; ++i) {
            float v = sp[m][i];
            v += __shfl_xor(v, 1, 64);
            v += __shfl_xor(v, 2, 64);
            v += __shfl_xor(v, 4, 64);
            v += __shfl_xor(v, 8, 64);
            if (cl == 0) scores_s[w * 32 + m * 16 + hi * 4 + i] = v;
        }
    }
    __syncthreads();

    // ---- block softmax over the 256 region scores ----
    float e = 0.f, sc = 0.f;
    if (t < RREG) { sc = scores_s[t]; F[t] = sc; }
    __syncthreads();
    for (int off = 128; off > 0; off >>= 1) {
        if (t < off) F[t] = fmaxf(F[t], F[t + off]);
        __syncthreads();
    }
    float mx = F[0];
    __syncthreads();
    if (t < RREG) { e = expf(sc - mx); F[t] = e; }
    __syncthreads();
    for (int off = 128; off > 0; off >>= 1) {
        if (t < off) F[t] += F[t + off];
        __syncthreads();
    }
    float denom = F[0];
    __syncthreads();
    if (t < RREG) {
        float al = e / denom;
        alpha_s[t] = al;
        out[FBAR_ELEMS + (size_t)g * RREG + t] = al;   // output 1: alphas
    }
    __syncthreads();

    // ---- pooling from register A-frags: fbar[d] = sum_r (alpha_r*inv_r)*x[r][d] ----
    {
        float wt0 = alpha_s[w * 32 + cl] * inv0;
        float wt1 = alpha_s[w * 32 + 16 + cl] * inv1;
        #pragma unroll
        for (int c = 0; c < 16; ++c) {
            #pragma unroll
            for (int j = 0; j < 8; ++j) {
                float vv = wt0 * bf2f((unsigned short)a0[c][j])
                         + wt1 * bf2f((unsigned short)a1[c][j]);
                vv += __shfl_xor(vv, 1, 64);
                vv += __shfl_xor(vv, 2, 64);
                vv += __shfl_xor(vv, 4, 64);
                vv += __shfl_xor(vv, 8, 64);
                if (cl == 0) wred[w * 512 + c * 32 + hi * 8 + j] = vv;
            }
        }
    }
    __syncthreads();
    {
        float s = 0.f;
        #pragma unroll
        for (int q = 0; q < 8; ++q) s += wred[q * 512 + t];
        out[(size_t)g * D + t] = s;                    // output 0: fbar
    }
}

extern "C" void kernel_launch(void* const* d_in, const int* in_sizes, int n_in,
                              void* d_out, int out_size, void* d_ws, size_t ws_size,
                              hipStream_t stream) {
    const float* x  = (const float*)d_in[0];
    const float* W1 = (const float*)d_in[1];
    const float* b1 = (const float*)d_in[2];
    const float* w2 = (const float*)d_in[3];
    // b2 (d_in[4]) shifts all scores uniformly -> softmax-invariant -> unused.
    float* out = (float*)d_out;

    unsigned short* W1s = (unsigned short*)d_ws;   // 512 KiB pre-swizzled bf16 W1

    conv_w1<<<256, 256, 0, stream>>>(W1, W1s);
    fused_group<<<NGROUP, 512, 0, stream>>>(x, W1s, b1, w2, out);
}

// Round 15
// 199.112 us; speedup vs baseline: 2.3349x; 2.3349x over previous
//
#include <hip/hip_runtime.h>
#include <hip/hip_bf16.h>

typedef short short8 __attribute__((ext_vector_type(8)));
typedef float floatx4 __attribute__((ext_vector_type(4)));

#define NGROUP 512
#define RREG 256
#define D 512
#define ROWS 131072
#define FBAR_ELEMS (NGROUP * D)   // 262144

__device__ __forceinline__ unsigned short f2bf(float f) {
    unsigned int u = __float_as_uint(f);
    unsigned int r = (u + 0x7fffu + ((u >> 16) & 1u)) >> 16;
    return (unsigned short)r;
}
__device__ __forceinline__ float fast_tanh(float x) {
    float cx = fminf(fmaxf(x, -9.5f), 9.5f);
    float e  = __builtin_amdgcn_exp2f(cx * 2.8853900817779268f);  // e^{2cx}
    return (e - 1.f) * __builtin_amdgcn_rcpf(e + 1.f);
}

// ---- kernel 1: W1 fp32 -> bf16, PRE-SWIZZLED full-K chunk image (R13 verbatim).
// Image ordered as 8 x (64 cols x 1 KiB-K-rows); a 32-col chunk nc is the
// contiguous 32 KiB at byte nc*32768; read-swizzle key (col&7)<<4 is the
// same whether addressed in 64- or 32-col chunks.
__global__ __launch_bounds__(256) void conv_w1(const float* __restrict__ W1,
                                               unsigned short* __restrict__ W1s) {
    int tid = blockIdx.x * 256 + threadIdx.x;   // 0..65535
    int G = tid * 8;                            // byte offset in 512 KiB
    int L = G & 65535;
    int col_local = L >> 10;
    int sw = L & 1023;
    int k16 = (sw ^ ((col_local & 7) << 4)) >> 4;
    int j0 = (sw & 15) >> 1;                    // 0 or 4
    int col = (G >> 16) * 64 + col_local;
    const float* src = W1 + col * 512 + k16 * 8 + j0;
    float4 v = *reinterpret_cast<const float4*>(src);
    ushort4 o;
    o.x = f2bf(v.x); o.y = f2bf(v.y); o.z = f2bf(v.z); o.w = f2bf(v.w);
    *reinterpret_cast<ushort4*>((char*)W1s + G) = o;
}

// ---- kernel 2: score GEMM — register-A, streamed-B, 2 blocks/CU ----
// 1024 blocks x 512 threads (8 waves). Wave owns 16 rows x all 512 cols.
// A: direct from global x in MFMA fragment layout, bf16-packed into a[16]
// (64 VGPR); normalize via 2 shuffles; no A-LDS (R13-proven).
// B: 32-col full-K chunks (32 KB) DMA'd into 2x32 KB LDS dbuf; 16 chunks,
// one __syncthreads per chunk, next stage issued AFTER the barrier into the
// buffer just freed (R13-proven schedule, ~600cy DMA cover).
// KEY CHANGE vs R13: LDS 131->64 KB => 2 blocks/CU = 4 waves/SIMD (R13
// post-mortem: no pipe >42% busy, pure latency exposure at 2 waves/SIMD).
// VGPR budget ~100 < the hard 128 cap (R14 lesson: cap is immovable).
__global__ __launch_bounds__(512) void score_gemm(
    const float* __restrict__ x, const unsigned short* __restrict__ W1s,
    const float* __restrict__ b1, const float* __restrict__ W2v,
    float* __restrict__ inv_norm, float* __restrict__ scores) {

    __shared__ char B_lds[2][32768];   // 64 KiB total

    const int t = threadIdx.x;
    const int lane = t & 63;
    const int w = t >> 6;          // wave 0..7
    const int cl = lane & 15;
    const int hi = lane >> 4;
    const size_t row0 = (size_t)blockIdx.x * 128;

    // cooperative stage of one 32-col chunk (32 KB): 4 KB per wave
    auto stage = [&](int buf, int nc) {
        const char* gb = (const char*)W1s + nc * 32768 + w * 4096 + lane * 16;
        char* lb = &B_lds[buf][w * 4096];
        #pragma unroll
        for (int i = 0; i < 4; ++i) {
            __builtin_amdgcn_global_load_lds(
                (const __attribute__((address_space(1))) void*)(gb + i * 1024),
                (__attribute__((address_space(3))) void*)(lb + i * 1024),
                16, 0, 0);
        }
    };

    stage(0, 0);   // chunks 0,1 in flight during the A phase
    stage(1, 1);

    // ---- A: 16 frags direct from x, bf16-pack, accumulate ss ----
    short8 a[16];
    float ss = 0.f;
    {
        const float* xp = x + (row0 + w * 16 + cl) * (size_t)D + hi * 8;
        #pragma unroll
        for (int c = 0; c < 16; ++c) {
            float4 p = *reinterpret_cast<const float4*>(xp + c * 32);
            float4 q = *reinterpret_cast<const float4*>(xp + c * 32 + 4);
            ss += p.x*p.x + p.y*p.y + p.z*p.z + p.w*p.w
                + q.x*q.x + q.y*q.y + q.z*q.z + q.w*q.w;
            short8 s8;
            s8[0] = (short)f2bf(p.x); s8[1] = (short)f2bf(p.y);
            s8[2] = (short)f2bf(p.z); s8[3] = (short)f2bf(p.w);
            s8[4] = (short)f2bf(q.x); s8[5] = (short)f2bf(q.y);
            s8[6] = (short)f2bf(q.z); s8[7] = (short)f2bf(q.w);
            a[c] = s8;
        }
    }
    // row cl's total lives in lanes {cl, cl+16, cl+32, cl+48}
    ss += __shfl_xor(ss, 16, 64);
    ss += __shfl_xor(ss, 32, 64);
    const float inv = 1.0f / fmaxf(sqrtf(ss), 1e-12f);
    if (lane < 16) inv_norm[row0 + w * 16 + cl] = inv;
    // accumulator row r = hi*4+i needs inv of row r (held by lane cl=r)
    float ivr[4];
    #pragma unroll
    for (int i = 0; i < 4; ++i) ivr[i] = __shfl(inv, hi * 4 + i, 16);

    __syncthreads();   // chunks 0,1 landed (barrier drains vmcnt)

    // ---- loop over 16 x 32-col chunks; fold tanh + w2-dot per chunk ----
    float sp[4] = {0.f, 0.f, 0.f, 0.f};

    for (int nc = 0; nc < 16; ++nc) {
        const char* Bb = &B_lds[nc & 1][0];
        floatx4 acc0{0,0,0,0}, acc1{0,0,0,0};

        #pragma unroll
        for (int s = 0; s < 16; ++s) {
            const int kb = s * 64 + hi * 16;
            short8 bf0 = *reinterpret_cast<const short8*>(
                Bb + cl * 1024 + (kb ^ ((cl & 7) << 4)));
            short8 bf1 = *reinterpret_cast<const short8*>(
                Bb + (16 + cl) * 1024 + (kb ^ ((cl & 7) << 4)));
            acc0 = __builtin_amdgcn_mfma_f32_16x16x32_bf16(a[s], bf0, acc0, 0, 0, 0);
            acc1 = __builtin_amdgcn_mfma_f32_16x16x32_bf16(a[s], bf1, acc1, 0, 0, 0);
        }

        {
            int col = nc * 32 + cl;
            float wv0 = W2v[col],      bb0 = b1[col];
            float wv1 = W2v[col + 16], bb1 = b1[col + 16];
            #pragma unroll
            for (int i = 0; i < 4; ++i) {
                sp[i] += wv0 * fast_tanh(acc0[i] * ivr[i] + bb0)
                       + wv1 * fast_tanh(acc1[i] * ivr[i] + bb1);
            }
        }

        __syncthreads();                          // all waves done with buf[nc&1];
                                                  // chunk nc+1 (issued last iter) drained
        if (nc + 2 < 16) stage(nc & 1, nc + 2);   // refill the buffer just freed
    }

    // ---- reduce score partials over the 16 col-lanes; C/D row = hi*4+i ----
    #pragma unroll
    for (int i = 0; i < 4; ++i) {
        float v = sp[i];
        v += __shfl_xor(v, 1, 64);
        v += __shfl_xor(v, 2, 64);
        v += __shfl_xor(v, 4, 64);
        v += __shfl_xor(v, 8, 64);
        if (cl == 0) scores[row0 + w * 16 + hi * 4 + i] = v;
    }
}

// ---- kernel 3: softmax over r + fp32 weighted pooling (proven) ----
__global__ __launch_bounds__(512) void softmax_pool(
    const float* __restrict__ x, const float* __restrict__ inv_norm,
    const float* __restrict__ scores, float* __restrict__ out) {

    __shared__ float F[RREG];
    __shared__ float wts[RREG];
    const int t = threadIdx.x;
    const int g = blockIdx.x;

    float s = 0.f, e = 0.f;
    if (t < RREG) { s = scores[g * RREG + t]; F[t] = s; }
    __syncthreads();
    for (int off = 128; off > 0; off >>= 1) {
        if (t < off) F[t] = fmaxf(F[t], F[t + off]);
        __syncthreads();
    }
    float mx = F[0];
    __syncthreads();
    if (t < RREG) { e = expf(s - mx); F[t] = e; }
    __syncthreads();
    for (int off = 128; off > 0; off >>= 1) {
        if (t < off) F[t] += F[t + off];
        __syncthreads();
    }
    float denom = F[0];
    if (t < RREG) {
        float al = e / denom;
        out[FBAR_ELEMS + (size_t)g * RREG + t] = al;          // output 1: alphas
        wts[t] = al * inv_norm[(size_t)g * RREG + t];
    }
    __syncthreads();

    // fbar[d=t] = sum_r (alpha_r * inv_r) * x[g,r,t]  (coalesced 2 KB/row)
    float a = 0.f;
    const float* xb = x + (size_t)g * RREG * D + t;
    #pragma unroll 16
    for (int r = 0; r < RREG; ++r) a += wts[r] * xb[(size_t)r * D];
    out[(size_t)g * D + t] = a;                               // output 0: fbar
}

extern "C" void kernel_launch(void* const* d_in, const int* in_sizes, int n_in,
                              void* d_out, int out_size, void* d_ws, size_t ws_size,
                              hipStream_t stream) {
    const float* x  = (const float*)d_in[0];
    const float* W1 = (const float*)d_in[1];
    const float* b1 = (const float*)d_in[2];
    const float* w2 = (const float*)d_in[3];
    // b2 (d_in[4]) shifts all scores uniformly -> softmax-invariant -> unused.
    float* out = (float*)d_out;

    unsigned short* W1s = (unsigned short*)d_ws;                     // 512 KiB
    float* inv_norm = (float*)((char*)d_ws + 524288);                // 512 KiB
    float* scores   = (float*)((char*)d_ws + 1048576);               // 512 KiB

    conv_w1<<<256, 256, 0, stream>>>(W1, W1s);
    score_gemm<<<ROWS / 128, 512, 0, stream>>>(x, W1s, b1, w2, inv_norm, scores);
    softmax_pool<<<NGROUP, 512, 0, stream>>>(x, inv_norm, scores, out);
}

// Round 16
// 160.092 us; speedup vs baseline: 2.9040x; 1.2437x over previous
//
#include <hip/hip_runtime.h>
#include <hip/hip_bf16.h>

typedef short short8 __attribute__((ext_vector_type(8)));
typedef float floatx4 __attribute__((ext_vector_type(4)));

#define NGROUP 512
#define RREG 256
#define D 512
#define ROWS 131072
#define FBAR_ELEMS (NGROUP * D)   // 262144

__device__ __forceinline__ unsigned short f2bf(float f) {
    unsigned int u = __float_as_uint(f);
    unsigned int r = (u + 0x7fffu + ((u >> 16) & 1u)) >> 16;
    return (unsigned short)r;
}
__device__ __forceinline__ float fast_tanh(float x) {
    float cx = fminf(fmaxf(x, -9.5f), 9.5f);
    float e  = __builtin_amdgcn_exp2f(cx * 2.8853900817779268f);  // e^{2cx}
    return (e - 1.f) * __builtin_amdgcn_rcpf(e + 1.f);
}

// ---- kernel 1: W1 fp32 -> bf16, K-CHUNKED PRE-SWIZZLED layout ----
// W1c = 16 chunks of 32 KiB. Chunk kc holds k in [kc*32,kc*32+32) for all 512
// cols: element (col, kc*32+kl) at chunk byte col*64 + ((kl*2) ^ (((col>>1)&3)<<4)).
// Swizzle key (col>>1)&3 (NOT col&3): within one ds_read_b128 the 8 same-parity
// cols get 4 distinct 16B slots -> uniform 2-way bank aliasing (free, m136);
// the old col&3 key left 4-way conflicts.
__global__ __launch_bounds__(256) void conv_w1(const float* __restrict__ W1,
                                               unsigned short* __restrict__ W1c) {
    int tid = blockIdx.x * 256 + threadIdx.x;   // 0..65535
    int P = tid * 8;                            // byte offset in 512 KiB image
    int kc = P >> 15;
    int L = P & 32767;
    int col = L >> 6;
    int q = L & 63;
    int kl = (q ^ (((col >> 1) & 3) << 4)) >> 1;   // multiple of 4
    const float* src = W1 + col * 512 + kc * 32 + kl;
    float4 v = *reinterpret_cast<const float4*>(src);
    ushort4 o;
    o.x = f2bf(v.x); o.y = f2bf(v.y); o.z = f2bf(v.z); o.w = f2bf(v.w);
    *reinterpret_cast<ushort4*>((char*)W1c + P) = o;
}

// ---- kernel 2: score GEMM, K-tiled A+B dbuf, VGPR<=64 for 4 waves/SIMD ----
// 2048 blocks x 512 threads (8 waves). Block = 64 rows x full N=512.
// R5..R15 occupancy law: waves/SIMD = floor(256/VGPR_Count); 43% occupancy
// iff VGPR<=64. __launch_bounds__(512,4) sets cap = 256/4 = 64 and allows
// 2 blocks/CU (LDS ~76.5KB x2 = 153KB <= 160KB). acc[4][4] lives in the
// separate 256-slot AGPR half (R5 precedent). Register diet: 1-step x
// prefetch (float4), shared A/B swizzle key, inv via LDS in epilogue only.
// Per K-step (BK=32): stage B(s+1) by DMA (wave-private slice), read 4 A +
// 4 B frags (reuse 2), 16 MFMA, pack A(s+1) from the prefetched x, barrier.
__global__ __launch_bounds__(512, 4) void score_gemm(
    const float* __restrict__ x, const unsigned short* __restrict__ W1c,
    const float* __restrict__ b1, const float* __restrict__ W2v,
    float* __restrict__ inv_norm, float* __restrict__ scores) {

    __shared__ unsigned short A_lds[2][64 * 32];    // 2 x 4 KB
    __shared__ unsigned short B_lds[2][512 * 32];   // 2 x 32 KB
    __shared__ float ss_lds[64][8];                 // 2 KB
    __shared__ float inv_s[64];
    __shared__ float scorebuf[8][64];               // 2 KB

    const int t = threadIdx.x;
    const int lane = t & 63;
    const int w = t >> 6;          // wave 0..7
    const int cl = lane & 15;
    const int hi = lane >> 4;
    const size_t row0 = (size_t)blockIdx.x * 64;

    // B stage: wave w DMAs its 64-col slice (4 KB) of chunk kc into B_lds[buf]
    auto stageB = [&](int buf, int kc) {
        const char* gb = (const char*)W1c + kc * 32768 + w * 4096 + lane * 16;
        char* lb = (char*)B_lds[buf] + w * 4096;
        #pragma unroll
        for (int i = 0; i < 4; ++i) {
            __builtin_amdgcn_global_load_lds(
                (const __attribute__((address_space(1))) void*)(gb + i * 1024),
                (__attribute__((address_space(3))) void*)(lb + i * 1024),
                16, 0, 0);
        }
    };

    // A staging: thread t owns row t>>3, k-quad t&7 of each 64x32 chunk.
    const int arow = t >> 3;
    const int abyte = arow * 64 + (((t & 7) * 8) ^ (((arow >> 1) & 3) << 4));
    const float* xbase = x + (row0 + arow) * (size_t)D + (t & 7) * 4;

    float ssacc = 0.f;
    auto packA = [&](int buf, const float4& xv) {
        ssacc += xv.x * xv.x + xv.y * xv.y + xv.z * xv.z + xv.w * xv.w;
        ushort4 pk;
        pk.x = f2bf(xv.x); pk.y = f2bf(xv.y); pk.z = f2bf(xv.z); pk.w = f2bf(xv.w);
        *reinterpret_cast<ushort4*>((char*)A_lds[buf] + abyte) = pk;
    };

    // ---- prologue: chunk 0 ----
    stageB(0, 0);
    {
        float4 xv = *reinterpret_cast<const float4*>(xbase);
        packA(0, xv);
    }
    __syncthreads();   // A(0) visible; B(0) DMA drained

    // ---- K loop: 16 steps of 32 k ----
    floatx4 acc[4][4];
    #pragma unroll
    for (int tt = 0; tt < 4; ++tt)
        #pragma unroll
        for (int f = 0; f < 4; ++f) acc[tt][f] = floatx4{0, 0, 0, 0};

    // shared fragment swizzle key: row=tt*16+cl and col=w*64+f*16+cl both
    // reduce to ((cl>>1)&3)<<4 (tile/wave offsets vanish mod 4)
    const int fswz = ((cl >> 1) & 3) << 4;
    const int fofs = (hi * 16) ^ fswz;

    #pragma unroll 2
    for (int s = 0; s < 16; ++s) {
        const int cur = s & 1, nx = cur ^ 1;

        float4 xv;
        if (s < 15) {
            xv = *reinterpret_cast<const float4*>(xbase + (s + 1) * 32);  // next A
            stageB(nx, s + 1);                                            // next B
        }

        short8 afr[4], bfr[4];
        #pragma unroll
        for (int tt = 0; tt < 4; ++tt)
            afr[tt] = *reinterpret_cast<const short8*>(
                (char*)A_lds[cur] + (tt * 16 + cl) * 64 + fofs);
        #pragma unroll
        for (int f = 0; f < 4; ++f)
            bfr[f] = *reinterpret_cast<const short8*>(
                (char*)B_lds[cur] + (w * 64 + f * 16 + cl) * 64 + fofs);

        #pragma unroll
        for (int tt = 0; tt < 4; ++tt)
            #pragma unroll
            for (int f = 0; f < 4; ++f)
                acc[tt][f] = __builtin_amdgcn_mfma_f32_16x16x32_bf16(
                    afr[tt], bfr[f], acc[tt][f], 0, 0, 0);

        if (s < 15) {
            packA(nx, xv);
            __syncthreads();   // A(s+1)/B(s+1) ready; all waves done with [cur]
        }
    }

    // ---- inv from accumulated ss ----
    ss_lds[arow][t & 7] = ssacc;
    __syncthreads();
    if (t < 64) {
        float ss = 0.f;
        #pragma unroll
        for (int j = 0; j < 8; ++j) ss += ss_lds[t][j];
        float inv = 1.0f / fmaxf(sqrtf(ss), 1e-12f);
        inv_s[t] = inv;
        inv_norm[row0 + t] = inv;
    }
    __syncthreads();

    // ---- epilogue: inv, tanh, w2-dot -> per-row partials for this col-slice ----
    float sp[4][4];
    #pragma unroll
    for (int tt = 0; tt < 4; ++tt)
        #pragma unroll
        for (int i = 0; i < 4; ++i) sp[tt][i] = 0.f;

    #pragma unroll
    for (int f = 0; f < 4; ++f) {
        int col = w * 64 + f * 16 + cl;
        float wv = W2v[col];
        float bb = b1[col];
        #pragma unroll
        for (int tt = 0; tt < 4; ++tt) {
            #pragma unroll
            for (int i = 0; i < 4; ++i) {
                float iv = inv_s[tt * 16 + hi * 4 + i];
                sp[tt][i] += wv * fast_tanh(acc[tt][f][i] * iv + bb);
            }
        }
    }

    // reduce over the 16 col-lanes; C/D row = hi*4+i within tile tt
    #pragma unroll
    for (int tt = 0; tt < 4; ++tt) {
        #pragma unroll
        for (int i = 0; i < 4; ++i) {
            float v = sp[tt][i];
            v += __shfl_xor(v, 1, 64);
            v += __shfl_xor(v, 2, 64);
            v += __shfl_xor(v, 4, 64);
            v += __shfl_xor(v, 8, 64);
            if (cl == 0) scorebuf[w][tt * 16 + hi * 4 + i] = v;
        }
    }
    __syncthreads();

    // sum the 8 per-wave col-slice partials -> final scores
    if (t < 64) {
        float s = 0.f;
        #pragma unroll
        for (int q = 0; q < 8; ++q) s += scorebuf[q][t];
        scores[row0 + t] = s;
    }
}

// ---- kernel 3: softmax over r + fp32 weighted pooling (proven) ----
__global__ __launch_bounds__(512) void softmax_pool(
    const float* __restrict__ x, const float* __restrict__ inv_norm,
    const float* __restrict__ scores, float* __restrict__ out) {

    __shared__ float F[RREG];
    __shared__ float wts[RREG];
    const int t = threadIdx.x;
    const int g = blockIdx.x;

    float s = 0.f, e = 0.f;
    if (t < RREG) { s = scores[g * RREG + t]; F[t] = s; }
    __syncthreads();
    for (int off = 128; off > 0; off >>= 1) {
        if (t < off) F[t] = fmaxf(F[t], F[t + off]);
        __syncthreads();
    }
    float mx = F[0];
    __syncthreads();
    if (t < RREG) { e = expf(s - mx); F[t] = e; }
    __syncthreads();
    for (int off = 128; off > 0; off >>= 1) {
        if (t < off) F[t] += F[t + off];
        __syncthreads();
    }
    float denom = F[0];
    if (t < RREG) {
        float al = e / denom;
        out[FBAR_ELEMS + (size_t)g * RREG + t] = al;          // output 1: alphas
        wts[t] = al * inv_norm[(size_t)g * RREG + t];
    }
    __syncthreads();

    // fbar[d=t] = sum_r (alpha_r * inv_r) * x[g,r,t]  (coalesced 2 KB/row)
    float a = 0.f;
    const float* xb = x + (size_t)g * RREG * D + t;
    #pragma unroll 16
    for (int r = 0; r < RREG; ++r) a += wts[r] * xb[(size_t)r * D];
    out[(size_t)g * D + t] = a;                               // output 0: fbar
}

extern "C" void kernel_launch(void* const* d_in, const int* in_sizes, int n_in,
                              void* d_out, int out_size, void* d_ws, size_t ws_size,
                              hipStream_t stream) {
    const float* x  = (const float*)d_in[0];
    const float* W1 = (const float*)d_in[1];
    const float* b1 = (const float*)d_in[2];
    const float* w2 = (const float*)d_in[3];
    // b2 (d_in[4]) shifts all scores uniformly -> softmax-invariant -> unused.
    float* out = (float*)d_out;

    unsigned short* W1c = (unsigned short*)d_ws;                     // 512 KiB
    float* inv_norm = (float*)((char*)d_ws + 524288);                // 512 KiB
    float* scores   = (float*)((char*)d_ws + 1048576);               // 512 KiB

    conv_w1<<<256, 256, 0, stream>>>(W1, W1c);
    score_gemm<<<ROWS / 64, 512, 0, stream>>>(x, W1c, b1, w2, inv_norm, scores);
    softmax_pool<<<NGROUP, 512, 0, stream>>>(x, inv_norm, scores, out);
}